// Round 1
// baseline (1300.997 us; speedup 1.0000x reference)
//
#include <hip/hip_runtime.h>
#include <hip/hip_bf16.h>

#define NUM_NODES 2000000
#define NUM_DAGS  20000
#define NF 5
#define NE 32
#define NH 64
#define DIN 37   // NF + NE

// LDS weight buffer offsets (floats)
#define W1OFF 0
#define W2OFF 2368
#define W3OFF 6464
#define B1OFF 8512
#define B2OFF 8576
#define B3OFF 8640
#define WTOT  8672

// Find largest s in [0, NUM_DAGS-1] with ptr[s*st] <= n.
// st = 1 for int32 ptr, 2 for int64 (little-endian low words).
__device__ __forceinline__ int seg_of(const int* __restrict__ ptr, int n, int st) {
    int lo = 0, hi = NUM_DAGS;
    while (hi - lo > 1) {
        int mid = (lo + hi) >> 1;
        if (ptr[mid * st] <= n) lo = mid; else hi = mid;
    }
    return lo;
}

__global__ __launch_bounds__(256, 2)
void dag_mlp_seg_kernel(const float* __restrict__ h_node,
                        const float* __restrict__ x,
                        const float* __restrict__ W1, const float* __restrict__ b1,
                        const float* __restrict__ W2, const float* __restrict__ b2,
                        const float* __restrict__ W3, const float* __restrict__ b3,
                        const int* __restrict__ ptr,
                        float* __restrict__ out) {
    __shared__ float sW[WTOT];
    __shared__ float sOut[128 * 33];   // half-block out spill, +1 pad per row

    const int tid = threadIdx.x;

    // ---- stage weights into LDS (wave-uniform broadcast reads later) ----
    for (int i = tid; i < 2368; i += 256) sW[W1OFF + i] = W1[i];
    for (int i = tid; i < 4096; i += 256) sW[W2OFF + i] = W2[i];
    for (int i = tid; i < 2048; i += 256) sW[W3OFF + i] = W3[i];
    if (tid < 64) { sW[B1OFF + tid] = b1[tid]; sW[B2OFF + tid] = b2[tid]; }
    if (tid < 32) sW[B3OFF + tid] = b3[tid];
    __syncthreads();

    // ptr dtype detect: int32 iff element NUM_DAGS (as int32) == NUM_NODES.
    // If the harness kept int64, low words sit at even int32 indices.
    const int pstride = (ptr[NUM_DAGS] == NUM_NODES) ? 1 : 2;

    const int blockStart = blockIdx.x * 256;
    const int n = blockStart + tid;

    float o[NE];

    if (n < NUM_NODES) {
        // ---- load input [x(5) | h_node(32)] ----
        float a[DIN];
        #pragma unroll
        for (int k = 0; k < NF; ++k) a[k] = x[(long)n * NF + k];
        const float4* hv = reinterpret_cast<const float4*>(h_node + (long)n * NE);
        #pragma unroll
        for (int q = 0; q < 8; ++q) {
            float4 v = hv[q];
            a[NF + 4*q + 0] = v.x; a[NF + 4*q + 1] = v.y;
            a[NF + 4*q + 2] = v.z; a[NF + 4*q + 3] = v.w;
        }

        // ---- layer 1: [37] -> relu[64] ----
        float h1[NH];
        #pragma unroll
        for (int j0 = 0; j0 < NH; j0 += 8) {
            float acc[8];
            #pragma unroll
            for (int jj = 0; jj < 8; ++jj) acc[jj] = sW[B1OFF + j0 + jj];
            #pragma unroll
            for (int k = 0; k < DIN; ++k) {
                float v = a[k];
                float4 wA = *reinterpret_cast<const float4*>(&sW[W1OFF + k*NH + j0]);
                float4 wB = *reinterpret_cast<const float4*>(&sW[W1OFF + k*NH + j0 + 4]);
                acc[0] += v * wA.x; acc[1] += v * wA.y; acc[2] += v * wA.z; acc[3] += v * wA.w;
                acc[4] += v * wB.x; acc[5] += v * wB.y; acc[6] += v * wB.z; acc[7] += v * wB.w;
            }
            #pragma unroll
            for (int jj = 0; jj < 8; ++jj) h1[j0 + jj] = fmaxf(acc[jj], 0.0f);
        }

        // ---- layer 2: [64] -> relu[64] ----
        float h2[NH];
        #pragma unroll
        for (int j0 = 0; j0 < NH; j0 += 8) {
            float acc[8];
            #pragma unroll
            for (int jj = 0; jj < 8; ++jj) acc[jj] = sW[B2OFF + j0 + jj];
            #pragma unroll
            for (int k = 0; k < NH; ++k) {
                float v = h1[k];
                float4 wA = *reinterpret_cast<const float4*>(&sW[W2OFF + k*NH + j0]);
                float4 wB = *reinterpret_cast<const float4*>(&sW[W2OFF + k*NH + j0 + 4]);
                acc[0] += v * wA.x; acc[1] += v * wA.y; acc[2] += v * wA.z; acc[3] += v * wA.w;
                acc[4] += v * wB.x; acc[5] += v * wB.y; acc[6] += v * wB.z; acc[7] += v * wB.w;
            }
            #pragma unroll
            for (int jj = 0; jj < 8; ++jj) h2[j0 + jj] = fmaxf(acc[jj], 0.0f);
        }

        // ---- layer 3: [64] -> [32] (no relu) ----
        #pragma unroll
        for (int j0 = 0; j0 < NE; j0 += 8) {
            float acc[8];
            #pragma unroll
            for (int jj = 0; jj < 8; ++jj) acc[jj] = sW[B3OFF + j0 + jj];
            #pragma unroll
            for (int k = 0; k < NH; ++k) {
                float v = h2[k];
                float4 wA = *reinterpret_cast<const float4*>(&sW[W3OFF + k*NE + j0]);
                float4 wB = *reinterpret_cast<const float4*>(&sW[W3OFF + k*NE + j0 + 4]);
                acc[0] += v * wA.x; acc[1] += v * wA.y; acc[2] += v * wA.z; acc[3] += v * wA.w;
                acc[4] += v * wB.x; acc[5] += v * wB.y; acc[6] += v * wB.z; acc[7] += v * wB.w;
            }
            #pragma unroll
            for (int jj = 0; jj < 8; ++jj) o[j0 + jj] = acc[jj];
        }
    }

    // ---- epilogue: segment-sum via LDS, two halves of 128 nodes ----
    #pragma unroll
    for (int half = 0; half < 2; ++half) {
        const int hStart = blockStart + half * 128;
        const int hEnd0  = hStart + 128;
        const int hEnd   = hEnd0 < NUM_NODES ? hEnd0 : NUM_NODES;
        __syncthreads();
        if ((tid >> 7) == half && n < NUM_NODES) {
            const int li = tid & 127;
            #pragma unroll
            for (int j = 0; j < NE; ++j) sOut[li * 33 + j] = o[j];
        }
        __syncthreads();
        if (hStart < NUM_NODES) {
            const int f = tid & 31;       // feature
            const int g = tid >> 5;       // segment group 0..7
            const int segFirst = seg_of(ptr, hStart, pstride);
            const int segLast  = seg_of(ptr, hEnd - 1, pstride);
            for (int s = segFirst + g; s <= segLast; s += 8) {
                int lo = ptr[s * pstride];
                int hi = ptr[(s + 1) * pstride];
                if (lo < hStart) lo = hStart;
                if (hi > hEnd)   hi = hEnd;
                float acc = 0.0f;
                for (int i = lo; i < hi; ++i) acc += sOut[(i - hStart) * 33 + f];
                if (hi > lo) atomicAdd(&out[s * NE + f], acc);
            }
        }
    }
}

extern "C" void kernel_launch(void* const* d_in, const int* in_sizes, int n_in,
                              void* d_out, int out_size, void* d_ws, size_t ws_size,
                              hipStream_t stream) {
    const float* h_node = (const float*)d_in[0];
    const float* x      = (const float*)d_in[1];
    const float* W1     = (const float*)d_in[2];
    const float* b1     = (const float*)d_in[3];
    const float* W2     = (const float*)d_in[4];
    const float* b2     = (const float*)d_in[5];
    const float* W3     = (const float*)d_in[6];
    const float* b3     = (const float*)d_in[7];
    const int*   ptr    = (const int*)d_in[8];
    float* out          = (float*)d_out;

    // harness poisons d_out with 0xAA before every launch; we accumulate with atomics
    hipMemsetAsync(out, 0, (size_t)out_size * sizeof(float), stream);

    const int grid = (NUM_NODES + 255) / 256;
    dag_mlp_seg_kernel<<<grid, 256, 0, stream>>>(h_node, x, W1, b1, W2, b2,
                                                 W3, b3, ptr, out);
}

// Round 2
// 629.988 us; speedup vs baseline: 2.0651x; 2.0651x over previous
//
#include <hip/hip_runtime.h>
#include <hip/hip_bf16.h>

typedef __bf16 bf16;
typedef __bf16 bf16x8 __attribute__((ext_vector_type(8)));
typedef float floatx4 __attribute__((ext_vector_type(4)));

#define NUM_NODES 2000000
#define NUM_DAGS  20000
#define NE 32

#define MFMA(a, b, c) __builtin_amdgcn_mfma_f32_16x16x32_bf16((a), (b), (c), 0, 0, 0)

// Find largest s in [0, NUM_DAGS-1] with ptr[s*st] <= n.
// st = 1 for int32 ptr, 2 for int64 (little-endian low words).
__device__ __forceinline__ int seg_of(const int* __restrict__ ptr, int n, int st) {
    int lo = 0, hi = NUM_DAGS;
    while (hi - lo > 1) {
        int mid = (lo + hi) >> 1;
        if (ptr[mid * st] <= n) lo = mid; else hi = mid;
    }
    return lo;
}

// K-order for layer 1: k0-31 = h_node[0..31] (W1 rows 5..36),
//                      k32-36 = x[0..4]      (W1 rows 0..4), k37-63 = zero pad.
// A/B fragment layouts (m89/m92/m120-verified):
//   A[m=lane&15][k=quad*8+j], B[k=quad*8+j][n=lane&15], D: col=lane&15, row=quad*4+reg.
// LDS activation rows: 16 rows x 64 bf16 (128B); 16B group p stored at position
// p^(m&7) within the row -> ds_read_b128 hits exactly 8 lanes per bank-group (optimal).

__global__ __launch_bounds__(256, 2)
void dag_mfma_kernel(const float* __restrict__ h_node,
                     const float* __restrict__ x,
                     const float* __restrict__ W1, const float* __restrict__ b1,
                     const float* __restrict__ W2, const float* __restrict__ b2,
                     const float* __restrict__ W3, const float* __restrict__ b3,
                     const int* __restrict__ ptr,
                     float* __restrict__ out) {
    __shared__ __align__(16) bf16 sIn[4][1024];   // per-wave input tile, pad-invariant
    __shared__ __align__(16) bf16 sH[4][1024];    // per-wave hidden tile (reused L1->L2->L3)
    __shared__ float sOut[128 * 36];              // per-round node outputs (pad 36: 2-way banks)

    const int tid = threadIdx.x;
    const int w   = tid >> 6;   // wave 0..3
    const int l   = tid & 63;
    const int q   = l >> 4;     // quad 0..3
    const int mr  = l & 15;

    // zero the input buffers once (pad groups stay zero forever: per-row write set is constant)
    for (int i = tid; i < 2048; i += 256) ((int*)sIn)[i] = 0;

    // ---- one-time: gather weight B-fragments into registers (L2-resident) ----
    bf16x8 w1f[2][4], w2f[2][4], w3f[2][2];
    float b1f[4], b2f[4], b3f[2];
    #pragma unroll
    for (int s = 0; s < 2; ++s) {
        #pragma unroll
        for (int tn = 0; tn < 4; ++tn) {
            #pragma unroll
            for (int j = 0; j < 8; ++j) {
                const int kk = s * 32 + q * 8 + j;
                const int row = (kk < 32) ? (kk + 5) : (kk < 37 ? kk - 32 : -1);
                const float v1v = (row >= 0) ? W1[row * 64 + tn * 16 + mr] : 0.0f;
                w1f[s][tn][j] = (bf16)v1v;
                w2f[s][tn][j] = (bf16)W2[kk * 64 + tn * 16 + mr];
                if (tn < 2) w3f[s][tn][j] = (bf16)W3[kk * 32 + tn * 16 + mr];
            }
        }
    }
    #pragma unroll
    for (int tn = 0; tn < 4; ++tn) {
        b1f[tn] = b1[tn * 16 + mr];
        b2f[tn] = b2[tn * 16 + mr];
    }
    b3f[0] = b3[mr]; b3f[1] = b3[16 + mr];

    const int pstride = (ptr[NUM_DAGS] == NUM_NODES) ? 1 : 2;
    const int blockStart = blockIdx.x * 512;

    __syncthreads();   // sIn zero-fill visible to all waves

    for (int R = 0; R < 4; ++R) {
        #pragma unroll
        for (int jj = 0; jj < 2; ++jj) {
            const int nodeBase = blockStart + (2 * R + jj) * 64 + w * 16;
            const int node = nodeBase + mr;

            // ---- stage input tile: 16 nodes x [h(32)|x(5)|pad] as bf16, swizzled ----
            if (node < NUM_NODES) {
                const float4* hp = reinterpret_cast<const float4*>(h_node + (size_t)node * 32 + q * 8);
                float4 v0 = hp[0], v1 = hp[1];
                bf16x8 fr;
                fr[0] = (bf16)v0.x; fr[1] = (bf16)v0.y; fr[2] = (bf16)v0.z; fr[3] = (bf16)v0.w;
                fr[4] = (bf16)v1.x; fr[5] = (bf16)v1.y; fr[6] = (bf16)v1.z; fr[7] = (bf16)v1.w;
                *(bf16x8*)&sIn[w][mr * 64 + ((q ^ (mr & 7)) * 8)] = fr;
                if (q == 0) {
                    const float* xp = x + (size_t)node * 5;
                    bf16x8 fx;
                    fx[0] = (bf16)xp[0]; fx[1] = (bf16)xp[1]; fx[2] = (bf16)xp[2];
                    fx[3] = (bf16)xp[3]; fx[4] = (bf16)xp[4];
                    fx[5] = (bf16)0.0f;  fx[6] = (bf16)0.0f;  fx[7] = (bf16)0.0f;
                    *(bf16x8*)&sIn[w][mr * 64 + ((4 ^ (mr & 7)) * 8)] = fx;
                }
            }
            asm volatile("s_waitcnt lgkmcnt(0)" ::: "memory");

            // ---- layer 1: [16x64] @ [64x64] -> relu -> sH ----
            bf16x8 a0 = *(const bf16x8*)&sIn[w][mr * 64 + ((q       ^ (mr & 7)) * 8)];
            bf16x8 a1 = *(const bf16x8*)&sIn[w][mr * 64 + (((4 + q) ^ (mr & 7)) * 8)];
            floatx4 c[4];
            #pragma unroll
            for (int tn = 0; tn < 4; ++tn) {
                c[tn] = (floatx4){b1f[tn], b1f[tn], b1f[tn], b1f[tn]};
                c[tn] = MFMA(a0, w1f[0][tn], c[tn]);
                c[tn] = MFMA(a1, w1f[1][tn], c[tn]);
            }
            #pragma unroll
            for (int tn = 0; tn < 4; ++tn) {
                #pragma unroll
                for (int r = 0; r < 4; ++r) {
                    const int m2 = q * 4 + r;
                    const int n  = tn * 16 + mr;
                    sH[w][m2 * 64 + ((n >> 3) ^ (m2 & 7)) * 8 + (n & 7)] = (bf16)fmaxf(c[tn][r], 0.0f);
                }
            }
            asm volatile("s_waitcnt lgkmcnt(0)" ::: "memory");

            // ---- layer 2: [16x64] @ [64x64] -> relu -> sH (in place; reads retired first) ----
            bf16x8 h0 = *(const bf16x8*)&sH[w][mr * 64 + ((q       ^ (mr & 7)) * 8)];
            bf16x8 h1 = *(const bf16x8*)&sH[w][mr * 64 + (((4 + q) ^ (mr & 7)) * 8)];
            #pragma unroll
            for (int tn = 0; tn < 4; ++tn) {
                c[tn] = (floatx4){b2f[tn], b2f[tn], b2f[tn], b2f[tn]};
                c[tn] = MFMA(h0, w2f[0][tn], c[tn]);
                c[tn] = MFMA(h1, w2f[1][tn], c[tn]);
            }
            #pragma unroll
            for (int tn = 0; tn < 4; ++tn) {
                #pragma unroll
                for (int r = 0; r < 4; ++r) {
                    const int m2 = q * 4 + r;
                    const int n  = tn * 16 + mr;
                    sH[w][m2 * 64 + ((n >> 3) ^ (m2 & 7)) * 8 + (n & 7)] = (bf16)fmaxf(c[tn][r], 0.0f);
                }
            }
            asm volatile("s_waitcnt lgkmcnt(0)" ::: "memory");

            // ---- layer 3: [16x64] @ [64x32] -> sOut (fp32) ----
            bf16x8 p0 = *(const bf16x8*)&sH[w][mr * 64 + ((q       ^ (mr & 7)) * 8)];
            bf16x8 p1 = *(const bf16x8*)&sH[w][mr * 64 + (((4 + q) ^ (mr & 7)) * 8)];
            floatx4 d0 = (floatx4){b3f[0], b3f[0], b3f[0], b3f[0]};
            floatx4 d1 = (floatx4){b3f[1], b3f[1], b3f[1], b3f[1]};
            d0 = MFMA(p0, w3f[0][0], d0);
            d0 = MFMA(p1, w3f[1][0], d0);
            d1 = MFMA(p0, w3f[0][1], d1);
            d1 = MFMA(p1, w3f[1][1], d1);
            #pragma unroll
            for (int r = 0; r < 4; ++r) {
                const int loc = jj * 64 + w * 16 + q * 4 + r;
                sOut[loc * 36 + mr]      = d0[r];
                sOut[loc * 36 + 16 + mr] = d1[r];
            }
        }
        __syncthreads();

        // ---- epilogue: segment-sum 128 nodes, 8 seg-groups x 32 features ----
        const int hStart = blockStart + R * 128;
        if (hStart < NUM_NODES) {
            const int hEnd0 = hStart + 128;
            const int hEnd  = hEnd0 < NUM_NODES ? hEnd0 : NUM_NODES;
            const int f = tid & 31;
            const int g = tid >> 5;
            const int segFirst = seg_of(ptr, hStart, pstride);
            const int segLast  = seg_of(ptr, hEnd - 1, pstride);
            for (int s = segFirst + g; s <= segLast; s += 8) {
                int lo = ptr[s * pstride];
                int hi = ptr[(s + 1) * pstride];
                if (lo < hStart) lo = hStart;
                if (hi > hEnd)   hi = hEnd;
                float acc = 0.0f;
                for (int i = lo; i < hi; ++i) acc += sOut[(i - hStart) * 36 + f];
                if (hi > lo) atomicAdd(&out[s * NE + f], acc);
            }
        }
        __syncthreads();
    }
}

extern "C" void kernel_launch(void* const* d_in, const int* in_sizes, int n_in,
                              void* d_out, int out_size, void* d_ws, size_t ws_size,
                              hipStream_t stream) {
    const float* h_node = (const float*)d_in[0];
    const float* x      = (const float*)d_in[1];
    const float* W1     = (const float*)d_in[2];
    const float* b1     = (const float*)d_in[3];
    const float* W2     = (const float*)d_in[4];
    const float* b2     = (const float*)d_in[5];
    const float* W3     = (const float*)d_in[6];
    const float* b3     = (const float*)d_in[7];
    const int*   ptr    = (const int*)d_in[8];
    float* out          = (float*)d_out;

    hipMemsetAsync(out, 0, (size_t)out_size * sizeof(float), stream);

    const int grid = (NUM_NODES + 511) / 512;   // 512 nodes per block
    dag_mfma_kernel<<<grid, 256, 0, stream>>>(h_node, x, W1, b1, W2, b2,
                                              W3, b3, ptr, out);
}

// Round 3
// 617.317 us; speedup vs baseline: 2.1075x; 1.0205x over previous
//
#include <hip/hip_runtime.h>
#include <hip/hip_bf16.h>

typedef __bf16 bf16;
typedef __bf16 bf16x4 __attribute__((ext_vector_type(4)));
typedef __bf16 bf16x8 __attribute__((ext_vector_type(8)));
typedef float  floatx4 __attribute__((ext_vector_type(4)));

#define NUM_NODES 2000000
#define NUM_DAGS  20000
#define NE 32

#define MFMA(a, b, c) __builtin_amdgcn_mfma_f32_16x16x32_bf16((a), (b), (c), 0, 0, 0)

#define ROW_BYTES  144           // 16 nodes/tile, 144 B per node-row (wire-speed LDS)
#define TILE_BYTES (16 * ROW_BYTES)

// Find largest s in [0, NUM_DAGS-1] with ptr[s*st] <= n.
// st = 1 for int32 ptr, 2 for int64 (little-endian low words).
__device__ __forceinline__ int seg_of(const int* __restrict__ ptr, int n, int st) {
    int lo = 0, hi = NUM_DAGS;
    while (hi - lo > 1) {
        int mid = (lo + hi) >> 1;
        if (ptr[mid * st] <= n) lo = mid; else hi = mid;
    }
    return lo;
}

// Transposed-domain MFMA pipeline: D[feat][node] = W^T . act^T.
//   A-frag (weights):    A[m=feat  = lane&15 (+16*mt)][k = quad*8+j]
//   B-frag (activation): B[k      = quad*8+j][n = node = lane&15]
//   D:                   D[feat = quad*4+reg (+16*mt)][node = lane&15]
// => D's 4 regs are 4 consecutive feats of ONE node: b64 packed LDS writes,
//    b128 LDS reads (8 consecutive feats of one node) for the next layer's B.
// Layer-1 K order: k0-31 = h_node[0..31] (W1 rows 5..36), k32-36 = x (W1 rows 0..4),
//                  k37: B=1.0, A=b1 (bias folded), k38-63 = 0.
__global__ __launch_bounds__(256, 2)
void dag_mfma_kernel(const float* __restrict__ h_node,
                     const float* __restrict__ x,
                     const float* __restrict__ W1, const float* __restrict__ b1,
                     const float* __restrict__ W2, const float* __restrict__ b2,
                     const float* __restrict__ W3, const float* __restrict__ b3,
                     const int* __restrict__ ptr,
                     float* __restrict__ out) {
    __shared__ __align__(16) char sBuf[16 * TILE_BYTES];   // 36,864 B

    const int tid = threadIdx.x;
    const int w   = tid >> 6;
    const int l   = tid & 63;
    const int q   = l >> 4;
    const int mr  = l & 15;

    // ---- weight A-fragments (one-time, L2-resident) ----
    bf16x8 w1f[2][4], w2f[2][4], w3f[2][2];
    #pragma unroll
    for (int s = 0; s < 2; ++s) {
        #pragma unroll
        for (int mt = 0; mt < 4; ++mt) {
            #pragma unroll
            for (int j = 0; j < 8; ++j) {
                const int kk  = s * 32 + q * 8 + j;
                const int col = mt * 16 + mr;
                float v1;
                if      (kk < 32)  v1 = W1[(kk + 5) * 64 + col];
                else if (kk < 37)  v1 = W1[(kk - 32) * 64 + col];
                else if (kk == 37) v1 = b1[col];
                else               v1 = 0.0f;
                w1f[s][mt][j] = (bf16)v1;
                w2f[s][mt][j] = (bf16)W2[kk * 64 + col];
                if (mt < 2) w3f[s][mt][j] = (bf16)W3[kk * 32 + mt * 16 + mr];
            }
        }
    }
    floatx4 b2f[4], b3f[2];
    #pragma unroll
    for (int mt = 0; mt < 4; ++mt)
        b2f[mt] = *(const floatx4*)(b2 + mt * 16 + q * 4);
    b3f[0] = *(const floatx4*)(b3 + q * 4);
    b3f[1] = *(const floatx4*)(b3 + 16 + q * 4);

    const int pstride    = (ptr[NUM_DAGS] == NUM_NODES) ? 1 : 2;
    const int blockStart = blockIdx.x * 256;

    // ---- global loads up front: activation B-frags for 4 tiles (64 nodes/wave) ----
    bf16x8 a0[4] = {}, a1[4] = {};
    #pragma unroll
    for (int j = 0; j < 4; ++j) {
        const int node = blockStart + w * 64 + j * 16 + mr;
        if (node < NUM_NODES) {
            const floatx4* hp = (const floatx4*)(h_node + (size_t)node * 32 + q * 8);
            floatx4 v0 = hp[0], v1 = hp[1];
            bf16x8 f;
            f[0] = (bf16)v0[0]; f[1] = (bf16)v0[1]; f[2] = (bf16)v0[2]; f[3] = (bf16)v0[3];
            f[4] = (bf16)v1[0]; f[5] = (bf16)v1[1]; f[6] = (bf16)v1[2]; f[7] = (bf16)v1[3];
            a0[j] = f;
            if (q == 0) {
                const float* xp = x + (size_t)node * 5;
                bf16x8 g = {};
                g[0] = (bf16)xp[0]; g[1] = (bf16)xp[1]; g[2] = (bf16)xp[2];
                g[3] = (bf16)xp[3]; g[4] = (bf16)xp[4];
                g[5] = (bf16)1.0f;                     // bias-1 slot (k=37)
                a1[j] = g;
            }
        }
    }

    char* myBuf = sBuf + (w * 4) * TILE_BYTES;

    // ---- phase A: layer 1 (global frags -> relu -> LDS) ----
    #pragma unroll
    for (int j = 0; j < 4; ++j) {
        floatx4 c[4] = {};
        #pragma unroll
        for (int mt = 0; mt < 4; ++mt) {
            c[mt] = MFMA(w1f[0][mt], a0[j], c[mt]);
            c[mt] = MFMA(w1f[1][mt], a1[j], c[mt]);
        }
        char* tb = myBuf + j * TILE_BYTES + mr * ROW_BYTES;
        #pragma unroll
        for (int mt = 0; mt < 4; ++mt) {
            bf16x4 v;
            v[0] = (bf16)fmaxf(c[mt][0], 0.0f);
            v[1] = (bf16)fmaxf(c[mt][1], 0.0f);
            v[2] = (bf16)fmaxf(c[mt][2], 0.0f);
            v[3] = (bf16)fmaxf(c[mt][3], 0.0f);
            *(bf16x4*)(tb + mt * 32 + q * 8) = v;      // feats mt*16+q*4 .. +3 of node mr
        }
    }

    // ---- phase B: layer 2 (LDS -> relu -> LDS, in place; DS in-order per wave,
    //      write data depends on read via MFMA so order is also compiler-safe) ----
    #pragma unroll
    for (int j = 0; j < 4; ++j) {
        char* tb = myBuf + j * TILE_BYTES + mr * ROW_BYTES;
        bf16x8 h0 = *(const bf16x8*)(tb + q * 16);        // feats q*8..+7
        bf16x8 h1 = *(const bf16x8*)(tb + 64 + q * 16);   // feats 32+q*8..+7
        floatx4 c[4];
        #pragma unroll
        for (int mt = 0; mt < 4; ++mt) {
            c[mt] = b2f[mt];
            c[mt] = MFMA(w2f[0][mt], h0, c[mt]);
            c[mt] = MFMA(w2f[1][mt], h1, c[mt]);
        }
        #pragma unroll
        for (int mt = 0; mt < 4; ++mt) {
            bf16x4 v;
            v[0] = (bf16)fmaxf(c[mt][0], 0.0f);
            v[1] = (bf16)fmaxf(c[mt][1], 0.0f);
            v[2] = (bf16)fmaxf(c[mt][2], 0.0f);
            v[3] = (bf16)fmaxf(c[mt][3], 0.0f);
            *(bf16x4*)(tb + mt * 32 + q * 8) = v;
        }
    }

    // ---- phase C: layer 3 (LDS -> fp32 out tile, aliases the bf16 buffer) ----
    #pragma unroll
    for (int j = 0; j < 4; ++j) {
        char* tb = myBuf + j * TILE_BYTES + mr * ROW_BYTES;
        bf16x8 p0 = *(const bf16x8*)(tb + q * 16);
        bf16x8 p1 = *(const bf16x8*)(tb + 64 + q * 16);
        floatx4 d0 = b3f[0], d1 = b3f[1];
        d0 = MFMA(w3f[0][0], p0, d0);
        d0 = MFMA(w3f[1][0], p1, d0);
        d1 = MFMA(w3f[0][1], p0, d1);
        d1 = MFMA(w3f[1][1], p1, d1);
        *(floatx4*)(tb + q * 16)      = d0;   // fp32 feats q*4..+3   of node mr
        *(floatx4*)(tb + 64 + q * 16) = d1;   // fp32 feats 16+q*4..+3
    }

    __syncthreads();

    // ---- epilogue: segment-sum over this block's 256 nodes ----
    {
        const int hStart = blockStart;
        const int hEnd0  = hStart + 256;
        const int hEnd   = hEnd0 < NUM_NODES ? hEnd0 : NUM_NODES;
        const int f = tid & 31;        // feature
        const int g = tid >> 5;        // segment group 0..7
        const int segFirst = seg_of(ptr, hStart, pstride);
        const int segLast  = seg_of(ptr, hEnd - 1, pstride);
        const float* so = (const float*)sBuf;
        for (int s = segFirst + g; s <= segLast; s += 8) {
            int lo = ptr[s * pstride];
            int hi = ptr[(s + 1) * pstride];
            if (lo < hStart) lo = hStart;
            if (hi > hEnd)   hi = hEnd;
            float acc = 0.0f;
            for (int i = lo; i < hi; ++i) {
                const int nl = i - hStart;
                acc += so[(nl >> 4) * 576 + (nl & 15) * 36 + f];
            }
            if (hi > lo) atomicAdd(&out[s * NE + f], acc);
        }
    }
}

extern "C" void kernel_launch(void* const* d_in, const int* in_sizes, int n_in,
                              void* d_out, int out_size, void* d_ws, size_t ws_size,
                              hipStream_t stream) {
    const float* h_node = (const float*)d_in[0];
    const float* x      = (const float*)d_in[1];
    const float* W1     = (const float*)d_in[2];
    const float* b1     = (const float*)d_in[3];
    const float* W2     = (const float*)d_in[4];
    const float* b2     = (const float*)d_in[5];
    const float* W3     = (const float*)d_in[6];
    const float* b3     = (const float*)d_in[7];
    const int*   ptr    = (const int*)d_in[8];
    float* out          = (float*)d_out;

    hipMemsetAsync(out, 0, (size_t)out_size * sizeof(float), stream);

    const int grid = (NUM_NODES + 255) / 256;   // 256 nodes per block
    dag_mfma_kernel<<<grid, 256, 0, stream>>>(h_node, x, W1, b1, W2, b2,
                                              W3, b3, ptr, out);
}